// Round 9
// baseline (442.577 us; speedup 1.0000x reference)
//
#include <hip/hip_runtime.h>

// VectorQuantizer: x (64,32,32,128) f32, embeddings (128,1024) f32.
// out = x + (q - x), q = e.T[argmin_k ||x_row - e_k||^2]
//
// Cascade (each stage only needs enough precision to RANK):
//   phase 1 (hi-bf16 MFMA, operands SWAPPED: A=codes, B=x-rows):
//     C-col = x-row (lane), C-reg = code -> per-row argmin is in-lane fmax over
//     packed keys (m = dot - nrm/2 with 8-bit code id in low mantissa bits).
//     -nrm/2 folded into a 9th MFMA (hi/lo bf16 at k=0,1 vs ones-column).
//     Grid = 512 rowgroups x 4 code-quarters; 8 hi-tiles staged ONCE in 64 KB
//     LDS via global_load_lds; barrier-free main loop.
//   merge: combine 4 quarters/row; s-gap < MARGIN1=0.6 -> wl1 (~8% rows).
//   rescan: one wave per wl1 row, f32 VALU over all 1024 codes (et L2-res);
//     gap < MARGIN2=3e-3 -> wl2 (~30 rows).
//   k_fix: exact f64 on wl2.
// A/B k-bijection symmetry + C/D layout (col=lane&31, reg->(r&3)+8*(r>>2)+
// 4*(lane>>5)) verified end-to-end by rounds 3-8 (absmax 0).

#define NROWS 65536
#define DDIM 128
#define KCODES 1024
#define MARGIN1 0.6f     // s-space
#define MARGIN2 3e-3f

typedef __attribute__((ext_vector_type(8))) short short8;
typedef __attribute__((ext_vector_type(16))) float f32x16;

__device__ inline ushort f2bf(float f) {            // RNE f32 -> bf16 bits
    union { float f; unsigned u; } v; v.f = f;
    unsigned r = v.u + 0x7fffu + ((v.u >> 16) & 1u);
    return (ushort)(r >> 16);
}
__device__ inline float bf2f(ushort b) {
    union { unsigned u; float f; } v; v.u = ((unsigned)b) << 16;
    return v.f;
}

__device__ inline void gload_lds16(const uint4* g, uint4* lds) {
    __builtin_amdgcn_global_load_lds((const __attribute__((address_space(1))) void*)g,
                                     (__attribute__((address_space(3))) void*)lds,
                                     16, 0, 0);
}

// ---------- fused prep: transpose + norms + bf16 hi pack + nrm hi/lo pack ----------
__global__ void k_prep(const float* __restrict__ e, float* __restrict__ et,
                       float* __restrict__ nrm, double* __restrict__ nrm64,
                       uint4* __restrict__ epq, unsigned* __restrict__ nhl) {
    const int gid = blockIdx.x * blockDim.x + threadIdx.x;   // 131072

    // transpose: et[k][d] = e[d][k]
    {
        int d = gid >> 10, k = gid & 1023;
        et[k * DDIM + d] = e[gid];
    }

    // pack hi fragments (first 16384 threads): epq[nt*512 + c*64 + lane]
    if (gid < 16384) {
        int lane = gid & 63, c = (gid >> 6) & 7, nt = gid >> 9;
        int col = nt * 32 + (lane & 31);
        int kbase = c * 16 + ((lane >> 5) << 3);
        union { ushort u[8]; uint4 q; } pk;
        #pragma unroll
        for (int j = 0; j < 8; ++j)
            pk.u[j] = f2bf(e[(kbase + j) * KCODES + col]);
        epq[(size_t)nt * 512 + c * 64 + lane] = pk.q;
    }

    // norms (threads 32768..40959): 8 lanes per code, shfl reduce
    if (gid >= 32768 && gid < 32768 + 8192) {
        int t2 = gid - 32768;
        int k = t2 >> 3, part = t2 & 7;
        double s = 0.0;
        #pragma unroll
        for (int j = 0; j < 16; ++j) {
            double v = (double)e[(part * 16 + j) * KCODES + k];
            s = fma(v, v, s);
        }
        #pragma unroll
        for (int m = 1; m < 8; m <<= 1) s += __shfl_xor(s, m);
        if (part == 0) {
            nrm64[k] = s; nrm[k] = (float)s;
            float t0 = (float)(-0.5 * s);               // -nrm/2, split hi/lo bf16
            ushort hb = f2bf(t0);
            ushort lb = f2bf(t0 - bf2f(hb));
            nhl[k] = (unsigned)hb | ((unsigned)lb << 16);
        }
    }
}

// ---------- phase 1: swapped-operand hi-bf16 MFMA argmin ----------
// grid 2048 = 512 rowgroups x 4 code-quarters. Block = 4 waves = 4 rowtiles.
// Stage-once 64 KB LDS (8 hi-tiles) + 1 KB nrm-hi/lo; barrier-free main loop.
__global__ __launch_bounds__(256, 2) void k_argmin32(const float* __restrict__ x,
                                                     const uint4* __restrict__ epq,
                                                     const unsigned* __restrict__ nhl,
                                                     unsigned* __restrict__ pb1,
                                                     float* __restrict__ pb2) {
    __shared__ uint4 sbuf[4096];      // 64 KB: 8 hi tiles
    __shared__ unsigned snhl[256];    // 1 KB: this quarter's -nrm/2 hi/lo

    const int tid = threadIdx.x;
    const int lane = tid & 63;
    const int w = tid >> 6;
    const int kq = blockIdx.x & 3;                 // code quarter
    const int rt = (blockIdx.x >> 2) * 4 + w;      // rowtile
    const int lrow = lane & 31;
    const int lgrp = lane >> 5;

    // stage quarter: 8 tiles (16 x 16B per thread) + nhl (wave 0)
    #pragma unroll
    for (int i = 0; i < 16; ++i)
        gload_lds16(epq + (size_t)kq * 4096 + i * 256 + tid,
                    &sbuf[i * 256 + (w << 6)]);
    if (tid < 64)
        gload_lds16(reinterpret_cast<const uint4*>(nhl) + kq * 64 + tid,
                    reinterpret_cast<uint4*>(snhl));

    // x hi fragments (B operand): col = x-row = rt*32+lrow, k(c,j) = c*16+lgrp*8+j
    const float* xr = x + (size_t)(rt * 32 + lrow) * DDIM + (lgrp << 3);
    short8 ah[8];
    #pragma unroll
    for (int c = 0; c < 8; ++c) {
        float4 u = *reinterpret_cast<const float4*>(xr + c * 16);
        float4 v = *reinterpret_cast<const float4*>(xr + c * 16 + 4);
        float fv[8] = {u.x, u.y, u.z, u.w, v.x, v.y, v.z, v.w};
        short8 hi;
        #pragma unroll
        for (int j = 0; j < 8; ++j) hi[j] = (short)f2bf(fv[j]);
        ah[c] = hi;
    }
    // extra-MFMA B operand: ones at k=0,1 (lgrp0 slots)
    short8 bx = {0, 0, 0, 0, 0, 0, 0, 0};
    if (lgrp == 0) { bx[0] = (short)0x3F80; bx[1] = (short)0x3F80; }

    asm volatile("s_waitcnt vmcnt(0)" ::: "memory");
    __syncthreads();                  // staging visible; no more barriers

    float kb1 = -3.4e38f, kb2 = -3.4e38f;
    const int cb4 = lgrp << 2;        // +4 term of the C/D row map

    for (int t = 0; t < 8; ++t) {
        f32x16 acc;
        #pragma unroll
        for (int r = 0; r < 16; ++r) acc[r] = 0.f;

        #pragma unroll
        for (int c = 0; c < 8; ++c) {
            union { uint4 q; short8 s; } ef;
            ef.q = sbuf[t * 512 + c * 64 + lane];
            acc = __builtin_amdgcn_mfma_f32_32x32x16_bf16(ef.s, ah[c], acc, 0, 0, 0);
        }
        // 9th MFMA: adds -nrm/2 (hi+lo) for each code-reg
        unsigned hl = snhl[t * 32 + lrow];
        short8 ax = {0, 0, 0, 0, 0, 0, 0, 0};
        if (lgrp == 0) { ax[0] = (short)(hl & 0xFFFF); ax[1] = (short)(hl >> 16); }
        acc = __builtin_amdgcn_mfma_f32_32x32x16_bf16(ax, bx, acc, 0, 0, 0);

        // in-lane argmax over packed keys (code id in low 8 mantissa bits)
        #pragma unroll
        for (int r = 0; r < 16; ++r) {
            unsigned cid = (unsigned)(t * 32 + (((r & 3) + ((r >> 2) << 3)) | cb4));
            float key = __uint_as_float((__float_as_uint(acc[r]) & 0xFFFFFF00u) | cid);
            kb2 = fmaxf(kb2, fminf(key, kb1));
            kb1 = fmaxf(kb1, key);
        }
    }

    // combine the two 32-lane halves (same row, complementary code subsets)
    float o1 = __shfl_xor(kb1, 32);
    float o2 = __shfl_xor(kb2, 32);
    float m1k = fmaxf(kb1, o1);
    float m2k = fmaxf(fmaxf(kb2, o2), fminf(kb1, o1));

    if (lane < 32) {
        size_t o = (size_t)kq * NROWS + rt * 32 + lrow;
        pb1[o] = __float_as_uint(m1k);
        pb2[o] = m2k;
    }
}

// ---------- merge 4 quarters per row ----------
__global__ void k_merge(const unsigned* __restrict__ pb1, const float* __restrict__ pb2,
                        int* __restrict__ idx, int* __restrict__ wlc,
                        int* __restrict__ wl) {
    int r = blockIdx.x * blockDim.x + threadIdx.x;     // 0..NROWS-1
    float best = -3.4e38f, sec = -3.4e38f; int bq = 0;
    #pragma unroll
    for (int q = 0; q < 4; ++q) {
        float k1 = __uint_as_float(pb1[(size_t)q * NROWS + r]);
        float k2 = pb2[(size_t)q * NROWS + r];
        bool t = k1 > best;
        sec = fmaxf(sec, fmaxf(k2, t ? best : k1));
        bq = t ? q : bq;
        best = t ? k1 : best;
    }
    unsigned ub = __float_as_uint(best);
    int code = bq * 256 + (int)(ub & 255u);
    float m1 = __uint_as_float(ub & 0xFFFFFF00u);
    float m2 = __uint_as_float(__float_as_uint(sec) & 0xFFFFFF00u);
    idx[r] = code;
    if (2.f * (m1 - m2) < MARGIN1) {                   // s-gap = 2*(m1-m2)
        int slot = atomicAdd(wlc, 1);
        wl[slot] = r;
    }
}

// ---------- rescan: one wave per flagged row, f32 VALU over all 1024 codes ----------
__global__ __launch_bounds__(256) void k_rescan(const float* __restrict__ x,
                                                const float* __restrict__ et,
                                                const float* __restrict__ nrm,
                                                const int* __restrict__ wlc,
                                                const int* __restrict__ wl,
                                                int* __restrict__ idx,
                                                int* __restrict__ wl2c,
                                                int* __restrict__ wl2) {
    __shared__ float xs[4][DDIM];
    const int tid = threadIdx.x, lane = tid & 63, wv = tid >> 6;
    const int n = *wlc;

    for (int i = blockIdx.x * 4 + wv; i < n; i += gridDim.x * 4) {
        const int row = wl[i];
        if (lane < 32)
            *reinterpret_cast<float4*>(&xs[wv][lane * 4]) =
                *reinterpret_cast<const float4*>(&x[(size_t)row * DDIM + lane * 4]);
        asm volatile("s_waitcnt vmcnt(0) lgkmcnt(0)" ::: "memory");

        float b1 = 3.4e38f, b2 = 3.4e38f; int bi = 0;
        for (int j = 0; j < 16; ++j) {
            int k = lane * 16 + j;                     // lane-order == code-order
            const float4* er = reinterpret_cast<const float4*>(et + (size_t)k * DDIM);
            float a0 = 0.f, a1 = 0.f, a2 = 0.f, a3 = 0.f;
            #pragma unroll
            for (int d4 = 0; d4 < 32; ++d4) {
                float4 ev = er[d4];
                float4 xv = *reinterpret_cast<const float4*>(&xs[wv][d4 * 4]);
                a0 = fmaf(ev.x, xv.x, a0);
                a1 = fmaf(ev.y, xv.y, a1);
                a2 = fmaf(ev.z, xv.z, a2);
                a3 = fmaf(ev.w, xv.w, a3);
            }
            float s = fmaf(-2.f, (a0 + a1) + (a2 + a3), nrm[k]);
            if (s < b1) { b2 = b1; b1 = s; bi = k; }
            else b2 = fminf(b2, s);
        }
        #pragma unroll
        for (int m = 1; m < 64; m <<= 1) {
            float o1 = __shfl_xor(b1, m);
            float o2 = __shfl_xor(b2, m);
            int   oi = __shfl_xor(bi, m);
            bool take = (o1 < b1) || (o1 == b1 && oi < bi);
            float loser = take ? b1 : o1;
            b1 = take ? o1 : b1;
            bi = take ? oi : bi;
            b2 = fminf(fminf(b2, o2), loser);
        }
        if (lane == 0) {
            idx[row] = bi;
            if (b2 - b1 < MARGIN2) {
                int slot = atomicAdd(wl2c, 1);
                wl2[slot] = row;
            }
        }
    }
}

// ---------- phase 3: exact f64 re-argmin, one row per block ----------
__global__ __launch_bounds__(256) void k_fix(const float* __restrict__ x,
                                             const float* __restrict__ e,
                                             const double* __restrict__ nrm64,
                                             const int* __restrict__ wlc,
                                             const int* __restrict__ wl,
                                             int* __restrict__ idx) {
    __shared__ float  xs[DDIM];
    __shared__ double w1[4]; __shared__ int wi[4];
    const int tid = threadIdx.x;
    const int lane = tid & 63;
    const int wv = tid >> 6;
    const int n = *wlc;

    for (int i = blockIdx.x; i < n; i += gridDim.x) {
        const int row = wl[i];
        if (tid < DDIM) xs[tid] = x[(size_t)row * DDIM + tid];
        __syncthreads();

        double dot[4] = {0.0, 0.0, 0.0, 0.0};
        for (int d0 = 0; d0 < DDIM; d0 += 8) {
            float ef[8][4];
            #pragma unroll
            for (int dd = 0; dd < 8; ++dd)
                #pragma unroll
                for (int kk = 0; kk < 4; ++kk)
                    ef[dd][kk] = e[(d0 + dd) * KCODES + tid + kk * 256];
            #pragma unroll
            for (int dd = 0; dd < 8; ++dd) {
                double xv = (double)xs[d0 + dd];
                #pragma unroll
                for (int kk = 0; kk < 4; ++kk)
                    dot[kk] = fma(xv, (double)ef[dd][kk], dot[kk]);
            }
        }

        double bb1 = 1e300; int bbi = 0;
        #pragma unroll
        for (int kk = 0; kk < 4; ++kk) {
            int k = tid + kk * 256;
            double sc = nrm64[k] - 2.0 * dot[kk];
            if (sc < bb1) { bb1 = sc; bbi = k; }
        }
        #pragma unroll
        for (int m = 1; m < 64; m <<= 1) {
            double o1 = __shfl_xor(bb1, m);
            int    oi = __shfl_xor(bbi, m);
            bool take = (o1 < bb1) || (o1 == bb1 && oi < bbi);
            bb1 = take ? o1 : bb1;
            bbi = take ? oi : bbi;
        }
        if (lane == 0) { w1[wv] = bb1; wi[wv] = bbi; }
        __syncthreads();
        if (tid == 0) {
            double f1 = w1[0]; int fi = wi[0];
            #pragma unroll
            for (int j = 1; j < 4; ++j) {
                bool take = (w1[j] < f1) || (w1[j] == f1 && wi[j] < fi);
                f1 = take ? w1[j] : f1;
                fi = take ? wi[j] : fi;
            }
            idx[row] = fi;
        }
        __syncthreads();
    }
}

// ---------- gather + f32 STE ----------
__global__ void k_gather(const float* __restrict__ x, const float* __restrict__ et,
                         const int* __restrict__ idxp, float* __restrict__ out) {
    int gid = blockIdx.x * blockDim.x + threadIdx.x;   // NROWS*32
    int row = gid >> 5, d4 = gid & 31;
    float4 q = reinterpret_cast<const float4*>(et)[(size_t)idxp[row] * 32 + d4];
    float4 xv = reinterpret_cast<const float4*>(x)[gid];
    float4 o;
    o.x = xv.x + (q.x - xv.x);
    o.y = xv.y + (q.y - xv.y);
    o.z = xv.z + (q.z - xv.z);
    o.w = xv.w + (q.w - xv.w);
    reinterpret_cast<float4*>(out)[gid] = o;
}

extern "C" void kernel_launch(void* const* d_in, const int* in_sizes, int n_in,
                              void* d_out, int out_size, void* d_ws, size_t ws_size,
                              hipStream_t stream) {
    const float* x = (const float*)d_in[0];
    const float* e = (const float*)d_in[1];
    float* out = (float*)d_out;

    // ws layout (f32 slot units; all segments 16B-aligned). Total ~3.7 MB.
    double*   nrm64 = (double*)d_ws;                     // 2048 slots
    float*    et    = (float*)d_ws + 2048;               // 131072
    float*    nrm   = et + 131072;                       // 1024
    int*      idx   = (int*)(nrm + 1024);                // 65536
    int*      wlc   = idx + NROWS;                       // 4 (wl1c, wl2c, pad)
    int*      wl    = wlc + 4;                           // 65536
    int*      wl2   = wl + NROWS;                        // 65536
    uint4*    epq   = (uint4*)(wl2 + NROWS);             // 16384 uint4 (hi only)
    unsigned* nhl   = (unsigned*)(epq + 16384);          // 1024
    unsigned* pb1   = nhl + 1024;                        // 4*65536
    float*    pb2   = (float*)(pb1 + 4 * NROWS);         // 4*65536

    hipMemsetAsync(wlc, 0, 2 * sizeof(int), stream);

    k_prep<<<512, 256, 0, stream>>>(e, et, nrm, nrm64, epq, nhl);
    k_argmin32<<<2048, 256, 0, stream>>>(x, epq, nhl, pb1, pb2);
    k_merge<<<NROWS / 256, 256, 0, stream>>>(pb1, pb2, idx, wlc, wl);
    k_rescan<<<1024, 256, 0, stream>>>(x, et, nrm, wlc, wl, idx, wlc + 1, wl2);
    k_fix<<<64, 256, 0, stream>>>(x, e, nrm64, wlc + 1, wl2, idx);
    k_gather<<<(NROWS * 32) / 256, 256, 0, stream>>>(x, et, idx, out);
}

// Round 10
// 101.665 us; speedup vs baseline: 4.3533x; 4.3533x over previous
//
#include <hip/hip_runtime.h>

// VectorQuantizer: x (64,32,32,128) f32, embeddings (128,1024) f32.
// out = x + (q - x), q = e.T[argmin_k ||x_row - e_k||^2]
//
// Cascade (each stage only needs enough precision to RANK):
//   phase 1 (hi-bf16 MFMA, swapped operands A=codes/B=x-rows): per-row argmin
//     in-lane over packed keys (m = dot - nrm/2, 7-bit code id in mantissa LSBs);
//     -nrm/2 folded in via 9th MFMA. Grid = 512 rowgroups x 8 code-eighths;
//     x pre-packed to bf16 fragments (in d_out scratch); 32.5 KB LDS stage-once.
//   merge: combine 8 eighths/row; s-gap < MARGIN1=0.30 -> wl1 (~2-4% rows).
//   rescan: 4 rows/block share one COALESCED d-major f32 e-sweep; block-reduce;
//     gap < MARGIN2=1e-3 -> wl2 (~10 rows).
//   k_fix: exact f64 on wl2.
// C/D layout col=lane&31, reg->(r&3)+8*(r>>2)+4*(lane>>5); k-bijection symmetry
// and the 9th-MFMA nrm trick verified end-to-end in rounds 3-9 (absmax 0).

#define NROWS 65536
#define DDIM 128
#define KCODES 1024
#define MARGIN1 0.30f    // s-space, hi-bf16 sigma ~0.035
#define MARGIN2 1e-3f    // f32-rescan sigma ~5e-5

typedef __attribute__((ext_vector_type(8))) short short8;
typedef __attribute__((ext_vector_type(16))) float f32x16;

__device__ inline ushort f2bf(float f) {            // RNE f32 -> bf16 bits
    union { float f; unsigned u; } v; v.f = f;
    unsigned r = v.u + 0x7fffu + ((v.u >> 16) & 1u);
    return (ushort)(r >> 16);
}
__device__ inline float bf2f(ushort b) {
    union { unsigned u; float f; } v; v.u = ((unsigned)b) << 16;
    return v.f;
}

__device__ inline void gload_lds16(const uint4* g, uint4* lds) {
    __builtin_amdgcn_global_load_lds((const __attribute__((address_space(1))) void*)g,
                                     (__attribute__((address_space(3))) void*)lds,
                                     16, 0, 0);
}

// ---------- fused prep: transpose + norms + e-hi pack + nrm hi/lo + x-hi pack ----------
// grid 4096 x 256 = 1,048,576 threads.
__global__ void k_prep(const float* __restrict__ x, const float* __restrict__ e,
                       float* __restrict__ et, float* __restrict__ nrm,
                       double* __restrict__ nrm64, uint4* __restrict__ epq,
                       unsigned* __restrict__ nhl, uint4* __restrict__ xp) {
    const int gid = blockIdx.x * blockDim.x + threadIdx.x;

    // x-hi fragment pack (all threads): xp[rt*512 + c*64 + lane]
    {
        int lane = gid & 63, c = (gid >> 6) & 7, rt = gid >> 9;     // rt 0..2047
        int row = rt * 32 + (lane & 31);
        int kbase = c * 16 + ((lane >> 5) << 3);
        const float4* xr4 = reinterpret_cast<const float4*>(x + (size_t)row * DDIM + kbase);
        float4 u = xr4[0], v = xr4[1];
        float fv[8] = {u.x, u.y, u.z, u.w, v.x, v.y, v.z, v.w};
        union { ushort s[8]; uint4 q; } pk;
        #pragma unroll
        for (int j = 0; j < 8; ++j) pk.s[j] = f2bf(fv[j]);
        xp[gid] = pk.q;
    }

    // transpose (first 131072): et[k][d] = e[d][k]
    if (gid < 131072) {
        int d = gid >> 10, k = gid & 1023;
        et[k * DDIM + d] = e[gid];
    }

    // e-hi fragment pack (first 16384): epq[nt*512 + c*64 + lane]
    if (gid < 16384) {
        int lane = gid & 63, c = (gid >> 6) & 7, nt = gid >> 9;
        int col = nt * 32 + (lane & 31);
        int kbase = c * 16 + ((lane >> 5) << 3);
        union { ushort s[8]; uint4 q; } pk;
        #pragma unroll
        for (int j = 0; j < 8; ++j)
            pk.s[j] = f2bf(e[(kbase + j) * KCODES + col]);
        epq[(size_t)nt * 512 + c * 64 + lane] = pk.q;
    }

    // norms (threads 32768..40959): 8 lanes per code, shfl reduce
    if (gid >= 32768 && gid < 32768 + 8192) {
        int t2 = gid - 32768;
        int k = t2 >> 3, part = t2 & 7;
        double s = 0.0;
        #pragma unroll
        for (int j = 0; j < 16; ++j) {
            double v = (double)e[(part * 16 + j) * KCODES + k];
            s = fma(v, v, s);
        }
        #pragma unroll
        for (int m = 1; m < 8; m <<= 1) s += __shfl_xor(s, m);
        if (part == 0) {
            nrm64[k] = s; nrm[k] = (float)s;
            float t0 = (float)(-0.5 * s);
            ushort hb = f2bf(t0);
            ushort lb = f2bf(t0 - bf2f(hb));
            nhl[k] = (unsigned)hb | ((unsigned)lb << 16);
        }
    }
}

// ---------- phase 1: swapped-operand hi-bf16 MFMA argmin, eighth-split ----------
// grid 4096 = 512 rowgroups x 8 code-eighths. Block = 4 waves = 4 rowtiles.
// 32 KB LDS (4 e-tiles) + 512 B nrm -> 4 blocks/CU runtime occupancy.
__global__ __launch_bounds__(256, 3) void k_argmin32(const uint4* __restrict__ xp,
                                                     const uint4* __restrict__ epq,
                                                     const unsigned* __restrict__ nhl,
                                                     unsigned* __restrict__ pb1,
                                                     float* __restrict__ pb2) {
    __shared__ uint4 sbuf[2048];      // 32 KB: 4 e-hi tiles
    __shared__ unsigned snhl[128];    // this eighth's -nrm/2 hi/lo

    const int tid = threadIdx.x;
    const int lane = tid & 63;
    const int w = tid >> 6;
    const int kq = blockIdx.x & 7;                 // code eighth
    const int rt = (blockIdx.x >> 3) * 4 + w;      // rowtile
    const int lrow = lane & 31;
    const int lgrp = lane >> 5;

    // stage eighth: 4 tiles (8 x 16B per thread) + nhl slice
    #pragma unroll
    for (int i = 0; i < 8; ++i)
        gload_lds16(epq + (size_t)kq * 2048 + i * 256 + tid,
                    &sbuf[i * 256 + (w << 6)]);
    if (tid < 32)
        gload_lds16(reinterpret_cast<const uint4*>(nhl) + kq * 32 + tid,
                    reinterpret_cast<uint4*>(snhl) + tid);

    // x-hi fragments (B operand), pre-packed: coalesced loads
    short8 ah[8];
    #pragma unroll
    for (int c = 0; c < 8; ++c) {
        union { uint4 q; short8 s; } u;
        u.q = xp[(size_t)rt * 512 + c * 64 + lane];
        ah[c] = u.s;
    }
    // 9th-MFMA B operand: ones at k=0,1
    short8 bx = {0, 0, 0, 0, 0, 0, 0, 0};
    if (lgrp == 0) { bx[0] = (short)0x3F80; bx[1] = (short)0x3F80; }

    int cidlow[16];
    #pragma unroll
    for (int r = 0; r < 16; ++r)
        cidlow[r] = (((r & 3) + ((r >> 2) << 3)) | (lgrp << 2));

    asm volatile("s_waitcnt vmcnt(0)" ::: "memory");
    __syncthreads();                  // staged; barrier-free main loop

    float kb1 = -3.4e38f, kb2 = -3.4e38f;

    for (int t = 0; t < 4; ++t) {
        f32x16 acc;
        #pragma unroll
        for (int r = 0; r < 16; ++r) acc[r] = 0.f;

        #pragma unroll
        for (int c = 0; c < 8; ++c) {
            union { uint4 q; short8 s; } ef;
            ef.q = sbuf[t * 512 + c * 64 + lane];
            acc = __builtin_amdgcn_mfma_f32_32x32x16_bf16(ef.s, ah[c], acc, 0, 0, 0);
        }
        unsigned hl = snhl[t * 32 + lrow];
        short8 ax = {0, 0, 0, 0, 0, 0, 0, 0};
        if (lgrp == 0) { ax[0] = (short)(hl & 0xFFFF); ax[1] = (short)(hl >> 16); }
        acc = __builtin_amdgcn_mfma_f32_32x32x16_bf16(ax, bx, acc, 0, 0, 0);

        #pragma unroll
        for (int r = 0; r < 16; ++r) {
            unsigned cid = (unsigned)((t << 5) | cidlow[r]);       // 0..127
            float key = __uint_as_float((__float_as_uint(acc[r]) & 0xFFFFFF00u) | cid);
            kb2 = fmaxf(kb2, fminf(key, kb1));
            kb1 = fmaxf(kb1, key);
        }
    }

    // combine the two 32-lane halves (same x-row, complementary code subsets)
    float o1 = __shfl_xor(kb1, 32);
    float o2 = __shfl_xor(kb2, 32);
    float m1k = fmaxf(kb1, o1);
    float m2k = fmaxf(fmaxf(kb2, o2), fminf(kb1, o1));

    if (lane < 32) {
        size_t o = (size_t)kq * NROWS + rt * 32 + lrow;
        pb1[o] = __float_as_uint(m1k);
        pb2[o] = m2k;
    }
}

// ---------- merge 8 eighths per row ----------
__global__ void k_merge(const unsigned* __restrict__ pb1, const float* __restrict__ pb2,
                        int* __restrict__ idx, int* __restrict__ wlc,
                        int* __restrict__ wl) {
    int r = blockIdx.x * blockDim.x + threadIdx.x;     // 0..NROWS-1
    float best = -3.4e38f, sec = -3.4e38f; int bq = 0;
    #pragma unroll
    for (int q = 0; q < 8; ++q) {
        float k1 = __uint_as_float(pb1[(size_t)q * NROWS + r]);
        float k2 = pb2[(size_t)q * NROWS + r];
        bool t = k1 > best;
        sec = fmaxf(sec, fmaxf(k2, t ? best : k1));
        bq = t ? q : bq;
        best = t ? k1 : best;
    }
    unsigned ub = __float_as_uint(best);
    int code = bq * 128 + (int)(ub & 255u);            // cid < 128
    float m1 = __uint_as_float(ub & 0xFFFFFF00u);
    float m2 = __uint_as_float(__float_as_uint(sec) & 0xFFFFFF00u);
    idx[r] = code;
    if (2.f * (m1 - m2) < MARGIN1) {                   // s-gap = 2*(m1-m2)
        int slot = atomicAdd(wlc, 1);
        wl[slot] = r;
    }
}

// ---------- rescan: 4 rows/block share one coalesced f32 e-sweep ----------
__global__ __launch_bounds__(256) void k_rescan(const float* __restrict__ x,
                                                const float* __restrict__ e,
                                                const float* __restrict__ nrm,
                                                const int* __restrict__ wlc,
                                                const int* __restrict__ wl,
                                                int* __restrict__ idx,
                                                int* __restrict__ wl2c,
                                                int* __restrict__ wl2) {
    __shared__ float xs[4][DDIM];
    __shared__ float rb1[4][256], rb2[4][256];
    __shared__ int   ri[4][256];
    const int tid = threadIdx.x, lane = tid & 63, wv = tid >> 6;
    const int n = *wlc;

    for (int i0 = blockIdx.x * 4; i0 < n; i0 += gridDim.x * 4) {
        if (tid < 128) {                   // 4 rows x 32 float4
            int j = tid >> 5, d4 = tid & 31;
            int ii = i0 + j;
            int row = wl[ii < n ? ii : i0];
            *reinterpret_cast<float4*>(&xs[j][d4 * 4]) =
                *reinterpret_cast<const float4*>(&x[(size_t)row * DDIM + d4 * 4]);
        }
        __syncthreads();

        float acc[4][4];
        #pragma unroll
        for (int kk = 0; kk < 4; ++kk)
            #pragma unroll
            for (int j = 0; j < 4; ++j) acc[kk][j] = 0.f;

        for (int d = 0; d < DDIM; d += 2) {
            float xv0[4], xv1[4];
            #pragma unroll
            for (int j = 0; j < 4; ++j) { xv0[j] = xs[j][d]; xv1[j] = xs[j][d + 1]; }
            #pragma unroll
            for (int kk = 0; kk < 4; ++kk) {
                float ev0 = e[d * KCODES + kk * 256 + tid];        // coalesced
                float ev1 = e[(d + 1) * KCODES + kk * 256 + tid];
                #pragma unroll
                for (int j = 0; j < 4; ++j) {
                    acc[kk][j] = fmaf(ev0, xv0[j], acc[kk][j]);
                    acc[kk][j] = fmaf(ev1, xv1[j], acc[kk][j]);
                }
            }
        }

        #pragma unroll
        for (int j = 0; j < 4; ++j) {
            float b1 = 3.4e38f, b2 = 3.4e38f; int bi = 0;
            #pragma unroll
            for (int kk = 0; kk < 4; ++kk) {
                int k = kk * 256 + tid;                 // ascending per thread
                float s = fmaf(-2.f, acc[kk][j], nrm[k]);
                if (s < b1) { b2 = b1; b1 = s; bi = k; }
                else b2 = fminf(b2, s);
            }
            rb1[j][tid] = b1; rb2[j][tid] = b2; ri[j][tid] = bi;
        }
        __syncthreads();

        // wave wv reduces row wv over 256 thread-entries
        {
            float b1 = 3.4e38f, b2 = 3.4e38f; int bi = 0;
            #pragma unroll
            for (int p = 0; p < 4; ++p) {
                int t2 = lane + p * 64;
                float o1 = rb1[wv][t2], o2 = rb2[wv][t2]; int oi = ri[wv][t2];
                bool take = (o1 < b1) || (o1 == b1 && oi < bi);
                float loser = take ? b1 : o1;
                b1 = take ? o1 : b1;
                bi = take ? oi : bi;
                b2 = fminf(fminf(b2, o2), loser);
            }
            #pragma unroll
            for (int m = 1; m < 64; m <<= 1) {
                float o1 = __shfl_xor(b1, m);
                float o2 = __shfl_xor(b2, m);
                int   oi = __shfl_xor(bi, m);
                bool take = (o1 < b1) || (o1 == b1 && oi < bi);
                float loser = take ? b1 : o1;
                b1 = take ? o1 : b1;
                bi = take ? oi : bi;
                b2 = fminf(fminf(b2, o2), loser);
            }
            if (lane == 0 && i0 + wv < n) {
                int row = wl[i0 + wv];
                idx[row] = bi;
                if (b2 - b1 < MARGIN2) {
                    int slot = atomicAdd(wl2c, 1);
                    wl2[slot] = row;
                }
            }
        }
        __syncthreads();
    }
}

// ---------- phase 3: exact f64 re-argmin, one row per block ----------
__global__ __launch_bounds__(256) void k_fix(const float* __restrict__ x,
                                             const float* __restrict__ e,
                                             const double* __restrict__ nrm64,
                                             const int* __restrict__ wlc,
                                             const int* __restrict__ wl,
                                             int* __restrict__ idx) {
    __shared__ float  xs[DDIM];
    __shared__ double w1[4]; __shared__ int wi[4];
    const int tid = threadIdx.x;
    const int lane = tid & 63;
    const int wv = tid >> 6;
    const int n = *wlc;

    for (int i = blockIdx.x; i < n; i += gridDim.x) {
        const int row = wl[i];
        if (tid < DDIM) xs[tid] = x[(size_t)row * DDIM + tid];
        __syncthreads();

        double dot[4] = {0.0, 0.0, 0.0, 0.0};
        for (int d0 = 0; d0 < DDIM; d0 += 8) {
            float ef[8][4];
            #pragma unroll
            for (int dd = 0; dd < 8; ++dd)
                #pragma unroll
                for (int kk = 0; kk < 4; ++kk)
                    ef[dd][kk] = e[(d0 + dd) * KCODES + tid + kk * 256];
            #pragma unroll
            for (int dd = 0; dd < 8; ++dd) {
                double xv = (double)xs[d0 + dd];
                #pragma unroll
                for (int kk = 0; kk < 4; ++kk)
                    dot[kk] = fma(xv, (double)ef[dd][kk], dot[kk]);
            }
        }

        double bb1 = 1e300; int bbi = 0;
        #pragma unroll
        for (int kk = 0; kk < 4; ++kk) {
            int k = tid + kk * 256;
            double sc = nrm64[k] - 2.0 * dot[kk];
            if (sc < bb1) { bb1 = sc; bbi = k; }
        }
        #pragma unroll
        for (int m = 1; m < 64; m <<= 1) {
            double o1 = __shfl_xor(bb1, m);
            int    oi = __shfl_xor(bbi, m);
            bool take = (o1 < bb1) || (o1 == bb1 && oi < bbi);
            bb1 = take ? o1 : bb1;
            bbi = take ? oi : bbi;
        }
        if (lane == 0) { w1[wv] = bb1; wi[wv] = bbi; }
        __syncthreads();
        if (tid == 0) {
            double f1 = w1[0]; int fi = wi[0];
            #pragma unroll
            for (int j = 1; j < 4; ++j) {
                bool take = (w1[j] < f1) || (w1[j] == f1 && wi[j] < fi);
                f1 = take ? w1[j] : f1;
                fi = take ? wi[j] : fi;
            }
            idx[row] = fi;
        }
        __syncthreads();
    }
}

// ---------- gather + f32 STE (overwrites ALL of d_out, incl. xp scratch) ----------
__global__ void k_gather(const float* __restrict__ x, const float* __restrict__ et,
                         const int* __restrict__ idxp, float* __restrict__ out) {
    int gid = blockIdx.x * blockDim.x + threadIdx.x;   // NROWS*32
    int row = gid >> 5, d4 = gid & 31;
    float4 q = reinterpret_cast<const float4*>(et)[(size_t)idxp[row] * 32 + d4];
    float4 xv = reinterpret_cast<const float4*>(x)[gid];
    float4 o;
    o.x = xv.x + (q.x - xv.x);
    o.y = xv.y + (q.y - xv.y);
    o.z = xv.z + (q.z - xv.z);
    o.w = xv.w + (q.w - xv.w);
    reinterpret_cast<float4*>(out)[gid] = o;
}

extern "C" void kernel_launch(void* const* d_in, const int* in_sizes, int n_in,
                              void* d_out, int out_size, void* d_ws, size_t ws_size,
                              hipStream_t stream) {
    const float* x = (const float*)d_in[0];
    const float* e = (const float*)d_in[1];
    float* out = (float*)d_out;

    // ws layout (f32 slot units; all segments 16B-aligned). ~5.6 MB.
    double*   nrm64 = (double*)d_ws;                     // 2048 slots
    float*    et    = (float*)d_ws + 2048;               // 131072
    float*    nrm   = et + 131072;                       // 1024
    int*      idx   = (int*)(nrm + 1024);                // 65536
    int*      wlc   = idx + NROWS;                       // 4 (wl1c, wl2c, pad)
    int*      wl    = wlc + 4;                           // 65536
    int*      wl2   = wl + NROWS;                        // 65536
    uint4*    epq   = (uint4*)(wl2 + NROWS);             // 16384 uint4 (e hi)
    unsigned* nhl   = (unsigned*)(epq + 16384);          // 1024
    unsigned* pb1   = nhl + 1024;                        // 8*65536
    float*    pb2   = (float*)(pb1 + 8 * NROWS);         // 8*65536
    // x-hi fragment pack lives in d_out (16 MB < 32 MB); k_gather overwrites it.
    uint4*    xp    = (uint4*)d_out;

    hipMemsetAsync(wlc, 0, 2 * sizeof(int), stream);

    k_prep<<<4096, 256, 0, stream>>>(x, e, et, nrm, nrm64, epq, nhl, xp);
    k_argmin32<<<4096, 256, 0, stream>>>(xp, epq, nhl, pb1, pb2);
    k_merge<<<NROWS / 256, 256, 0, stream>>>(pb1, pb2, idx, wlc, wl);
    k_rescan<<<768, 256, 0, stream>>>(x, e, nrm, wlc, wl, idx, wlc + 1, wl2);
    k_fix<<<64, 256, 0, stream>>>(x, e, nrm64, wlc + 1, wl2, idx);
    k_gather<<<(NROWS * 32) / 256, 256, 0, stream>>>(x, et, idx, out);
}

// Round 11
// 95.349 us; speedup vs baseline: 4.6416x; 1.0662x over previous
//
#include <hip/hip_runtime.h>

// VectorQuantizer: x (64,32,32,128) f32, embeddings (128,1024) f32.
// out = x + (q - x), q = e.T[argmin_k ||x_row - e_k||^2]
//
// Cascade (each stage only needs enough precision to RANK):
//   phase 1 (hi-bf16 MFMA, swapped operands A=codes/B=x-rows): per-row argmin
//     in-lane over packed keys (m = dot - nrm/2, 7-bit code id in mantissa LSBs);
//     -nrm/2 folded in via 9th MFMA. Grid = 256 rowgroups(256 rows) x 8 eighths;
//     per wave TWO rowtiles with INTERLEAVED acc chains (MFMA ILP=2, shared
//     B-fragment ds_reads). x pre-packed bf16 (d_out scratch); 32 KB stage-once.
//   merge: 8 eighths/row; s-gap < MARGIN1=0.30 -> wl (~3-5% rows).
//   rescan: EXACT f64 re-argmin, 4 rows/block, coalesced d-major e-sweep.
// 5 dispatches total (wlc cleared by prep; k_fix folded into rescan).
// C/D layout col=lane&31, reg->(r&3)+8*(r>>2)+4*(lane>>5); k-bijection symmetry
// and the 9th-MFMA nrm trick verified end-to-end rounds 3-10 (absmax 0).

#define NROWS 65536
#define DDIM 128
#define KCODES 1024
#define MARGIN1 0.30f    // s-space; hi-bf16 sigma ~0.05-0.09, empirically clean

typedef __attribute__((ext_vector_type(8))) short short8;
typedef __attribute__((ext_vector_type(16))) float f32x16;

__device__ inline ushort f2bf(float f) {            // RNE f32 -> bf16 bits
    union { float f; unsigned u; } v; v.f = f;
    unsigned r = v.u + 0x7fffu + ((v.u >> 16) & 1u);
    return (ushort)(r >> 16);
}
__device__ inline float bf2f(ushort b) {
    union { unsigned u; float f; } v; v.u = ((unsigned)b) << 16;
    return v.f;
}

__device__ inline void gload_lds16(const uint4* g, uint4* lds) {
    __builtin_amdgcn_global_load_lds((const __attribute__((address_space(1))) void*)g,
                                     (__attribute__((address_space(3))) void*)lds,
                                     16, 0, 0);
}

// ---------- fused prep: transpose + norms + e-hi pack + nrm hi/lo + x-hi pack ----------
// grid 4096 x 256.
__global__ void k_prep(const float* __restrict__ x, const float* __restrict__ e,
                       float* __restrict__ et, float* __restrict__ nrm,
                       double* __restrict__ nrm64, uint4* __restrict__ epq,
                       unsigned* __restrict__ nhl, uint4* __restrict__ xp,
                       int* __restrict__ wlc) {
    const int gid = blockIdx.x * blockDim.x + threadIdx.x;

    if (gid == 0) { wlc[0] = 0; wlc[1] = 0; }

    // x-hi fragment pack (all threads): xp[rt*512 + c*64 + lane]
    {
        int lane = gid & 63, c = (gid >> 6) & 7, rt = gid >> 9;     // rt 0..2047
        int row = rt * 32 + (lane & 31);
        int kbase = c * 16 + ((lane >> 5) << 3);
        const float4* xr4 = reinterpret_cast<const float4*>(x + (size_t)row * DDIM + kbase);
        float4 u = xr4[0], v = xr4[1];
        float fv[8] = {u.x, u.y, u.z, u.w, v.x, v.y, v.z, v.w};
        union { ushort s[8]; uint4 q; } pk;
        #pragma unroll
        for (int j = 0; j < 8; ++j) pk.s[j] = f2bf(fv[j]);
        xp[gid] = pk.q;
    }

    // transpose (first 131072): et[k][d] = e[d][k]
    if (gid < 131072) {
        int d = gid >> 10, k = gid & 1023;
        et[k * DDIM + d] = e[gid];
    }

    // e-hi fragment pack (first 16384): epq[nt*512 + c*64 + lane]
    if (gid < 16384) {
        int lane = gid & 63, c = (gid >> 6) & 7, nt = gid >> 9;
        int col = nt * 32 + (lane & 31);
        int kbase = c * 16 + ((lane >> 5) << 3);
        union { ushort s[8]; uint4 q; } pk;
        #pragma unroll
        for (int j = 0; j < 8; ++j)
            pk.s[j] = f2bf(e[(kbase + j) * KCODES + col]);
        epq[(size_t)nt * 512 + c * 64 + lane] = pk.q;
    }

    // norms (threads 32768..40959): 8 lanes per code, shfl reduce
    if (gid >= 32768 && gid < 32768 + 8192) {
        int t2 = gid - 32768;
        int k = t2 >> 3, part = t2 & 7;
        double s = 0.0;
        #pragma unroll
        for (int j = 0; j < 16; ++j) {
            double v = (double)e[(part * 16 + j) * KCODES + k];
            s = fma(v, v, s);
        }
        #pragma unroll
        for (int m = 1; m < 8; m <<= 1) s += __shfl_xor(s, m);
        if (part == 0) {
            nrm64[k] = s; nrm[k] = (float)s;
            float t0 = (float)(-0.5 * s);
            ushort hb = f2bf(t0);
            ushort lb = f2bf(t0 - bf2f(hb));
            nhl[k] = (unsigned)hb | ((unsigned)lb << 16);
        }
    }
}

// ---------- phase 1: swapped-operand hi-bf16 MFMA argmin ----------
// grid 2048 = 256 rowgroups x 8 code-eighths. Block = 4 waves; each wave owns
// TWO rowtiles (interleaved MFMA chains). 32 KB LDS stage-once; barrier-free loop.
__global__ __launch_bounds__(256, 3) void k_argmin32(const uint4* __restrict__ xp,
                                                     const uint4* __restrict__ epq,
                                                     const unsigned* __restrict__ nhl,
                                                     unsigned* __restrict__ pb1,
                                                     float* __restrict__ pb2) {
    __shared__ uint4 sbuf[2048];      // 32 KB: 4 e-hi tiles
    __shared__ unsigned snhl[128];    // this eighth's -nrm/2 hi/lo

    const int tid = threadIdx.x;
    const int lane = tid & 63;
    const int w = tid >> 6;
    const int kq = blockIdx.x & 7;                 // code eighth
    const int rg = blockIdx.x >> 3;                // rowgroup (256 rows)
    const int rtA = rg * 8 + w * 2;                // this wave's rowtiles
    const int rtB = rtA + 1;
    const int lrow = lane & 31;
    const int lgrp = lane >> 5;

    // stage eighth: 4 tiles (8 x 16B per thread) + nhl slice
    #pragma unroll
    for (int i = 0; i < 8; ++i)
        gload_lds16(epq + (size_t)kq * 2048 + i * 256 + tid,
                    &sbuf[i * 256 + (w << 6)]);
    if (tid < 32)
        gload_lds16(reinterpret_cast<const uint4*>(nhl) + kq * 32 + tid,
                    reinterpret_cast<uint4*>(snhl));

    // x-hi fragments for both rowtiles (pre-packed, coalesced)
    short8 ahA[8], ahB[8];
    #pragma unroll
    for (int c = 0; c < 8; ++c) {
        union { uint4 q; short8 s; } ua, ub;
        ua.q = xp[(size_t)rtA * 512 + c * 64 + lane];
        ub.q = xp[(size_t)rtB * 512 + c * 64 + lane];
        ahA[c] = ua.s; ahB[c] = ub.s;
    }
    // 9th-MFMA B operand: ones at k=0,1
    short8 bx = {0, 0, 0, 0, 0, 0, 0, 0};
    if (lgrp == 0) { bx[0] = (short)0x3F80; bx[1] = (short)0x3F80; }

    int cidlow[16];
    #pragma unroll
    for (int r = 0; r < 16; ++r)
        cidlow[r] = (((r & 3) + ((r >> 2) << 3)) | (lgrp << 2));

    asm volatile("s_waitcnt vmcnt(0)" ::: "memory");
    __syncthreads();                  // staged; barrier-free main loop

    float kA1 = -3.4e38f, kA2 = -3.4e38f;
    float kB1 = -3.4e38f, kB2 = -3.4e38f;

    for (int t = 0; t < 4; ++t) {
        f32x16 aA, aB;
        #pragma unroll
        for (int r = 0; r < 16; ++r) { aA[r] = 0.f; aB[r] = 0.f; }

        #pragma unroll
        for (int c = 0; c < 8; ++c) {
            union { uint4 q; short8 s; } ef;
            ef.q = sbuf[t * 512 + c * 64 + lane];
            aA = __builtin_amdgcn_mfma_f32_32x32x16_bf16(ef.s, ahA[c], aA, 0, 0, 0);
            aB = __builtin_amdgcn_mfma_f32_32x32x16_bf16(ef.s, ahB[c], aB, 0, 0, 0);
        }
        unsigned hl = snhl[t * 32 + lrow];
        short8 ax = {0, 0, 0, 0, 0, 0, 0, 0};
        if (lgrp == 0) { ax[0] = (short)(hl & 0xFFFF); ax[1] = (short)(hl >> 16); }
        aA = __builtin_amdgcn_mfma_f32_32x32x16_bf16(ax, bx, aA, 0, 0, 0);
        aB = __builtin_amdgcn_mfma_f32_32x32x16_bf16(ax, bx, aB, 0, 0, 0);

        #pragma unroll
        for (int r = 0; r < 16; ++r) {
            unsigned cid = (unsigned)((t << 5) | cidlow[r]);       // 0..127
            float keyA = __uint_as_float((__float_as_uint(aA[r]) & 0xFFFFFF00u) | cid);
            float keyB = __uint_as_float((__float_as_uint(aB[r]) & 0xFFFFFF00u) | cid);
            kA2 = fmaxf(kA2, fminf(keyA, kA1));
            kA1 = fmaxf(kA1, keyA);
            kB2 = fmaxf(kB2, fminf(keyB, kB1));
            kB1 = fmaxf(kB1, keyB);
        }
    }

    // combine the two 32-lane halves (same x-row, complementary code subsets)
    {
        float o1 = __shfl_xor(kA1, 32);
        float o2 = __shfl_xor(kA2, 32);
        float m1 = fmaxf(kA1, o1);
        float m2 = fmaxf(fmaxf(kA2, o2), fminf(kA1, o1));
        if (lane < 32) {
            size_t o = (size_t)kq * NROWS + rtA * 32 + lrow;
            pb1[o] = __float_as_uint(m1);
            pb2[o] = m2;
        }
    }
    {
        float o1 = __shfl_xor(kB1, 32);
        float o2 = __shfl_xor(kB2, 32);
        float m1 = fmaxf(kB1, o1);
        float m2 = fmaxf(fmaxf(kB2, o2), fminf(kB1, o1));
        if (lane < 32) {
            size_t o = (size_t)kq * NROWS + rtB * 32 + lrow;
            pb1[o] = __float_as_uint(m1);
            pb2[o] = m2;
        }
    }
}

// ---------- merge 8 eighths per row ----------
__global__ void k_merge(const unsigned* __restrict__ pb1, const float* __restrict__ pb2,
                        int* __restrict__ idx, int* __restrict__ wlc,
                        int* __restrict__ wl) {
    int r = blockIdx.x * blockDim.x + threadIdx.x;     // 0..NROWS-1
    float best = -3.4e38f, sec = -3.4e38f; int bq = 0;
    #pragma unroll
    for (int q = 0; q < 8; ++q) {
        float k1 = __uint_as_float(pb1[(size_t)q * NROWS + r]);
        float k2 = pb2[(size_t)q * NROWS + r];
        bool t = k1 > best;
        sec = fmaxf(sec, fmaxf(k2, t ? best : k1));
        bq = t ? q : bq;
        best = t ? k1 : best;
    }
    unsigned ub = __float_as_uint(best);
    int code = bq * 128 + (int)(ub & 255u);            // cid < 128
    float m1 = __uint_as_float(ub & 0xFFFFFF00u);
    float m2 = __uint_as_float(__float_as_uint(sec) & 0xFFFFFF00u);
    idx[r] = code;
    if (2.f * (m1 - m2) < MARGIN1) {                   // s-gap = 2*(m1-m2)
        int slot = atomicAdd(wlc, 1);
        wl[slot] = r;
    }
}

// ---------- rescan: EXACT f64 re-argmin, 4 rows/block, coalesced e-sweep ----------
__global__ __launch_bounds__(256) void k_rescan(const float* __restrict__ x,
                                                const float* __restrict__ e,
                                                const double* __restrict__ nrm64,
                                                const int* __restrict__ wlc,
                                                const int* __restrict__ wl,
                                                int* __restrict__ idx) {
    __shared__ float  xs[4][DDIM];
    __shared__ double rb1[4][256];
    __shared__ int    ri[4][256];
    const int tid = threadIdx.x, lane = tid & 63, wv = tid >> 6;
    const int n = *wlc;

    for (int i0 = blockIdx.x * 4; i0 < n; i0 += gridDim.x * 4) {
        if (tid < 128) {                   // 4 rows x 32 float4
            int j = tid >> 5, d4 = tid & 31;
            int ii = i0 + j;
            int row = wl[ii < n ? ii : i0];
            *reinterpret_cast<float4*>(&xs[j][d4 * 4]) =
                *reinterpret_cast<const float4*>(&x[(size_t)row * DDIM + d4 * 4]);
        }
        __syncthreads();

        double acc[4][4];
        #pragma unroll
        for (int kk = 0; kk < 4; ++kk)
            #pragma unroll
            for (int j = 0; j < 4; ++j) acc[kk][j] = 0.0;

        for (int d = 0; d < DDIM; d += 2) {
            double xv0[4], xv1[4];
            #pragma unroll
            for (int j = 0; j < 4; ++j) {
                xv0[j] = (double)xs[j][d];
                xv1[j] = (double)xs[j][d + 1];
            }
            #pragma unroll
            for (int kk = 0; kk < 4; ++kk) {
                double ev0 = (double)e[d * KCODES + kk * 256 + tid];       // coalesced
                double ev1 = (double)e[(d + 1) * KCODES + kk * 256 + tid];
                #pragma unroll
                for (int j = 0; j < 4; ++j) {
                    acc[kk][j] = fma(ev0, xv0[j], acc[kk][j]);
                    acc[kk][j] = fma(ev1, xv1[j], acc[kk][j]);
                }
            }
        }

        #pragma unroll
        for (int j = 0; j < 4; ++j) {
            double b1 = 1e300; int bi = 0;
            #pragma unroll
            for (int kk = 0; kk < 4; ++kk) {
                int k = kk * 256 + tid;                 // ascending per thread
                double s = nrm64[k] - 2.0 * acc[kk][j];
                if (s < b1) { b1 = s; bi = k; }
            }
            rb1[j][tid] = b1; ri[j][tid] = bi;
        }
        __syncthreads();

        // wave wv reduces row wv over 256 thread-entries (first-min tiebreak)
        {
            double b1 = 1e300; int bi = 0x7FFFFFFF;
            #pragma unroll
            for (int p = 0; p < 4; ++p) {
                int t2 = lane + p * 64;
                double o1 = rb1[wv][t2]; int oi = ri[wv][t2];
                bool take = (o1 < b1) || (o1 == b1 && oi < bi);
                b1 = take ? o1 : b1;
                bi = take ? oi : bi;
            }
            #pragma unroll
            for (int m = 1; m < 64; m <<= 1) {
                double o1 = __shfl_xor(b1, m);
                int    oi = __shfl_xor(bi, m);
                bool take = (o1 < b1) || (o1 == b1 && oi < bi);
                b1 = take ? o1 : b1;
                bi = take ? oi : bi;
            }
            if (lane == 0 && i0 + wv < n)
                idx[wl[i0 + wv]] = bi;
        }
        __syncthreads();
    }
}

// ---------- gather + f32 STE (overwrites ALL of d_out, incl. xp scratch) ----------
__global__ void k_gather(const float* __restrict__ x, const float* __restrict__ et,
                         const int* __restrict__ idxp, float* __restrict__ out) {
    int gid = blockIdx.x * blockDim.x + threadIdx.x;   // NROWS*32
    int row = gid >> 5, d4 = gid & 31;
    float4 q = reinterpret_cast<const float4*>(et)[(size_t)idxp[row] * 32 + d4];
    float4 xv = reinterpret_cast<const float4*>(x)[gid];
    float4 o;
    o.x = xv.x + (q.x - xv.x);
    o.y = xv.y + (q.y - xv.y);
    o.z = xv.z + (q.z - xv.z);
    o.w = xv.w + (q.w - xv.w);
    reinterpret_cast<float4*>(out)[gid] = o;
}

extern "C" void kernel_launch(void* const* d_in, const int* in_sizes, int n_in,
                              void* d_out, int out_size, void* d_ws, size_t ws_size,
                              hipStream_t stream) {
    const float* x = (const float*)d_in[0];
    const float* e = (const float*)d_in[1];
    float* out = (float*)d_out;

    // ws layout (f32 slot units; all segments 16B-aligned). ~5.6 MB.
    double*   nrm64 = (double*)d_ws;                     // 2048 slots
    float*    et    = (float*)d_ws + 2048;               // 131072
    float*    nrm   = et + 131072;                       // 1024
    int*      idx   = (int*)(nrm + 1024);                // 65536
    int*      wlc   = idx + NROWS;                       // 4
    int*      wl    = wlc + 4;                           // 65536
    uint4*    epq   = (uint4*)(wl + NROWS);              // 16384 uint4 (e hi)
    unsigned* nhl   = (unsigned*)(epq + 16384);          // 1024
    unsigned* pb1   = nhl + 1024;                        // 8*65536
    float*    pb2   = (float*)(pb1 + 8 * NROWS);         // 8*65536
    // x-hi fragment pack lives in d_out (16 MB < 32 MB); k_gather overwrites it.
    uint4*    xp    = (uint4*)d_out;

    k_prep<<<4096, 256, 0, stream>>>(x, e, et, nrm, nrm64, epq, nhl, xp, wlc);
    k_argmin32<<<2048, 256, 0, stream>>>(xp, epq, nhl, pb1, pb2);
    k_merge<<<NROWS / 256, 256, 0, stream>>>(pb1, pb2, idx, wlc, wl);
    k_rescan<<<1024, 256, 0, stream>>>(x, e, nrm64, wlc, wl, idx);
    k_gather<<<(NROWS * 32) / 256, 256, 0, stream>>>(x, et, idx, out);
}